// Round 7
// baseline (524.353 us; speedup 1.0000x reference)
//
#include <hip/hip_runtime.h>
#include <hip/hip_bf16.h>
#include <math.h>

#define TB 4
#define TT 4096
#define HH 2048
#define DD 256
#define NN 32768
#define HQ 512
#define MM (TB*TT)

typedef __attribute__((ext_vector_type(8))) short bf16x8;
typedef __attribute__((ext_vector_type(8))) _Float16 f16x8;
typedef __attribute__((ext_vector_type(4))) float f32x4;

__device__ inline unsigned short f2bf(float x){
  __hip_bfloat16 h = __float2bfloat16(x);
  return *reinterpret_cast<unsigned short*>(&h);
}

__device__ inline unsigned short f2h(float x){
  _Float16 h = (_Float16)x;
  unsigned short u; __builtin_memcpy(&u, &h, 2); return u;
}

__device__ inline bf16x8 as_bf16x8(uint4 u){ bf16x8 r; __builtin_memcpy(&r,&u,16); return r; }

// async global->LDS DMA, 16B per lane. LDS dest = wave-uniform base + lane*16;
// global source is per-lane.
__device__ __forceinline__ void gload_ldsv(const void* g, void* l){
  __builtin_amdgcn_global_load_lds(
      (const __attribute__((address_space(1))) unsigned int*)g,
      (__attribute__((address_space(3))) unsigned int*)l, 16, 0, 0);
}

// K_prep: fused preprocessing — batch-mean (8192 blocks) + cvt_w (1024) +
// cvt_wobs (512) + beliefs-normalize (8192) + z1/z2/flag zeroing (129).
#define PREP_MEAN 8192
#define PREP_CVTW 1024
#define PREP_WOBS 512
#define PREP_BEL  8192
#define PREP_ZERO 129
#define PREP_GRID (PREP_MEAN+PREP_CVTW+PREP_WOBS+PREP_BEL+PREP_ZERO)
__global__ __launch_bounds__(256) void k_prep(
    const float* __restrict__ h, unsigned short* __restrict__ hmb,
    const float* __restrict__ Wg1, const float* __restrict__ Wp1,
    unsigned short* __restrict__ Wsw,
    const float* __restrict__ Wobs, unsigned short* __restrict__ wob,
    const float* __restrict__ bel, unsigned short* __restrict__ bbf,
    unsigned int* __restrict__ zbase){
  const int b = blockIdx.x;
  if (b < PREP_MEAN){
    const size_t i = (size_t)b*256 + threadIdx.x;
    const size_t TH4 = (size_t)TT*HH/4;
    const float4* p = (const float4*)h;
    float4 v0 = p[i], v1 = p[i+TH4], v2 = p[i+2*TH4], v3 = p[i+3*TH4];
    float4 m;
    m.x = 0.25f*(v0.x+v1.x+v2.x+v3.x);
    m.y = 0.25f*(v0.y+v1.y+v2.y+v3.y);
    m.z = 0.25f*(v0.z+v1.z+v2.z+v3.z);
    m.w = 0.25f*(v0.w+v1.w+v2.w+v3.w);
    ushort4 o; o.x = f2bf(m.x); o.y = f2bf(m.y); o.z = f2bf(m.z); o.w = f2bf(m.w);
    *(ushort4*)(hmb + i*4) = o;
  } else if (b < PREP_MEAN + PREP_CVTW){
    const int id = (b - PREP_MEAN)*256 + threadIdx.x;
    const int n = id >> 8;
    const int cg = id & 255;
    const int k = cg*8;
    const int kc = cg >> 2;
    const int c8 = cg & 3;
    const float* src = (n < HQ) ? (Wg1 + (size_t)n*HH + k) : (Wp1 + (size_t)(n-HQ)*HH + k);
    float4 v0 = *(const float4*)src;
    float4 v1 = *(const float4*)(src + 4);
    unsigned short o[8] = {f2h(v0.x),f2h(v0.y),f2h(v0.z),f2h(v0.w),
                           f2h(v1.x),f2h(v1.y),f2h(v1.z),f2h(v1.w)};
    const int nb = n >> 8, r = n & 255;
    const int s = (r & 3) ^ ((r >> 2) & 3);
    unsigned short* dst = Wsw + ((size_t)(nb*64 + kc))*8192 + r*32 + ((c8 ^ s) << 3);
    __builtin_memcpy(dst, o, 16);
  } else if (b < PREP_MEAN + PREP_CVTW + PREP_WOBS){
    const int idx4 = (b - PREP_MEAN - PREP_CVTW)*256 + threadIdx.x;
    float4 v = *(const float4*)(Wobs + (size_t)idx4*4);
    ushort4 o; o.x = f2bf(v.x); o.y = f2bf(v.y); o.z = f2bf(v.z); o.w = f2bf(v.w);
    *(ushort4*)(wob + (size_t)idx4*4) = o;
  } else if (b < PREP_MEAN + PREP_CVTW + PREP_WOBS + PREP_BEL){
    const int bb = b - (PREP_MEAN + PREP_CVTW + PREP_WOBS);
    const int n = (bb*256 + threadIdx.x) >> 6;
    const int lane = threadIdx.x & 63;
    const float4 v = *(const float4*)(bel + (size_t)n*DD + lane*4);
    float s = v.x*v.x + v.y*v.y + v.z*v.z + v.w*v.w;
    #pragma unroll
    for (int m = 1; m < 64; m <<= 1) s += __shfl_xor(s, m);
    const float inv = 1.f / fmaxf(sqrtf(s), 1e-8f);
    ushort4 o;
    o.x = f2bf(v.x*inv); o.y = f2bf(v.y*inv); o.z = f2bf(v.z*inv); o.w = f2bf(v.w*inv);
    *(ushort4*)(bbf + (size_t)n*DD + lane*4) = o;
  } else {
    const int idx = (b - (PREP_MEAN + PREP_CVTW + PREP_WOBS + PREP_BEL))*256 + threadIdx.x;
    if (idx < 32832) zbase[idx] = 0;
  }
}

// K3: obs_mean GEMM + fused obs_fin epilogue (unchanged from round 6).
__global__ __launch_bounds__(256) void k_obs(const unsigned short* __restrict__ A,
    const unsigned short* __restrict__ Bw,
    const float* __restrict__ z1, const float* __restrict__ z2,
    const float* __restrict__ bg2, const float* __restrict__ bp2,
    float* __restrict__ out0, float* __restrict__ out3,
    unsigned short* __restrict__ obf,
    const unsigned char* __restrict__ mask, int* __restrict__ flag){
  const int blk = blockIdx.x;
  const int tid = threadIdx.x;
  if (blk >= 64){   // any-active part
    const int i = (blk - 64)*256 + tid;
    const int any = (mask[i] != 0) ? 1 : 0;
    if (__ballot(any)){
      if ((tid & 63) == 0) atomicOr(flag, 1);
    }
    return;
  }
  const int m0 = blk*64;
  const int w = tid>>6, lane = tid&63, lr = lane&15, q = lane>>4;
  __shared__ __align__(16) unsigned short As[2][64*32];    // 2 x 4 KB
  __shared__ __align__(16) unsigned short Bs[2][256*32];   // 2 x 16 KB
  f32x4 acc[16] = {};
  const int srow = lane >> 2, sch = (lane & 3) ^ (srow & 3);
  const unsigned short* asrc = A + (size_t)(m0 + w*16 + srow)*HH + sch*8;

  gload_ldsv(asrc, &As[0][w*16*32]);
  #pragma unroll
  for (int i = 0; i < 4; i++){
    const unsigned short* bsrc = Bw + (size_t)((i*4 + w)*16 + srow)*HH + sch*8;
    gload_ldsv(bsrc, &Bs[0][(i*4 + w)*16*32]);
  }
  __syncthreads();
  const int px = (q ^ (lr & 3)) << 3;
  for (int t = 0; t < 64; t++){
    const int cur = t & 1;
    if (t < 63){
      const int ko = (t+1)*32;
      gload_ldsv(asrc + ko, &As[cur^1][w*16*32]);
      #pragma unroll
      for (int i = 0; i < 4; i++){
        const unsigned short* bsrc = Bw + (size_t)((i*4 + w)*16 + srow)*HH + ko + sch*8;
        gload_ldsv(bsrc, &Bs[cur^1][(i*4 + w)*16*32]);
      }
    }
    bf16x8 a = as_bf16x8(*(const uint4*)&As[cur][(w*16 + lr)*32 + px]);
    #pragma unroll
    for (int j = 0; j < 16; j++){
      bf16x8 bb = as_bf16x8(*(const uint4*)&Bs[cur][(j*16 + lr)*32 + px]);
      acc[j] = __builtin_amdgcn_mfma_f32_16x16x32_bf16(a, bb, acc[j], 0, 0, 0);
    }
    __syncthreads();
  }
  #pragma unroll
  for (int r = 0; r < 4; r++){
    const int t = m0 + w*16 + q*4 + r;
    float s2 = 0.f;
    #pragma unroll
    for (int j = 0; j < 16; j++) s2 += acc[j][r]*acc[j][r];
    #pragma unroll
    for (int mk = 1; mk < 16; mk <<= 1) s2 += __shfl_xor(s2, mk);
    const float nrm = sqrtf(s2);
    float p = 0.f;
    #pragma unroll
    for (int bb = 0; bb < TB; bb++){
      float a = z1[bb*TT + t] + bg2[0];
      float c = z2[bb*TT + t] + bp2[0];
      float gate = 1.f/(1.f + expf(-a));
      float sp = (c > 0.f) ? (c + log1pf(expf(-c))) : log1pf(expf(c));
      p += gate * sp;
    }
    const float pm = p * 0.25f;
    const float sc = pm / fmaxf(nrm, 1e-8f);
    float qq = 0.f;
    #pragma unroll
    for (int j = 0; j < 16; j++){
      float o = acc[j][r] * sc;
      out0[(size_t)t*DD + j*16 + lr] = o;
      qq += o*o;
    }
    #pragma unroll
    for (int mk = 1; mk < 16; mk <<= 1) qq += __shfl_xor(qq, mk);
    const float r2 = sqrtf(qq);
    const float inv2 = 1.f / fmaxf(r2, 1e-8f);
    #pragma unroll
    for (int j = 0; j < 16; j++){
      float o = acc[j][r] * sc;
      obf[(size_t)t*DD + j*16 + lr] = f2bf(o * inv2);
    }
    if (lr == 0) out3[t] = (r2 > 0.05f) ? 1.f : 0.f;
  }
}

// K4: gate/prec layer1. NEW: BM=256 (512-thread block, 8 waves, 1 block/CU).
// Rationale: at BM=128 the kernel was LDS-BW-bound — each wave reads the full
// 16KB W tile, so per-CU LDS traffic (160KB/step) matched MFMA cycles. Doubling
// BM doubles MFMA work per step at UNCHANGED per-CU LDS traffic -> MFMA-bound.
// LDS 96KB: Ws 2x16KB + As 2x32KB. Same full-DMA double-buffer schedule.
__global__ __launch_bounds__(512, 2) void k_gp(const float* __restrict__ A,
    const unsigned short* __restrict__ Wsw,
    const float* __restrict__ bg1, const float* __restrict__ bp1,
    const float* __restrict__ Wg2, const float* __restrict__ Wp2,
    float* __restrict__ z1, float* __restrict__ z2){
  // bijective XCD-grouping: 4 nb-blocks sharing an A-panel land on one XCD
  const int bid = blockIdx.x;            // 0..255
  const int s5 = bid >> 3;               // 0..31
  const int nb = s5 & 3;
  const int my = ((s5 >> 2) << 3) | (bid & 7);   // 0..63
  const int m0 = my*256;
  const int tid = threadIdx.x;
  const int w = tid>>6, lane = tid&63, lr = lane&15, q = lane>>4;
  __shared__ __align__(16) unsigned short Ws[2][8192];   // 2 x 16 KB
  __shared__ __align__(16) float As[2][8192];            // 2 x 32 KB
  f32x4 acc[2][16] = {};

  // W staging: 8 waves x 2 instrs x 1KB = 16KB (linear copy of swizzled tile)
  const unsigned short* wtp = Wsw + (size_t)nb*64*8192 + w*1024 + lane*8;
  const int rpB = lr*32 + ((q ^ ((lr & 3) ^ ((lr >> 2) & 3))) << 3);
  // A staging: 8 waves x 4 instrs x 8 rows; slot s of row r holds chunk s^(r&7)
  const int sr8 = lane >> 3;
  const int sc  = (lane & 7) ^ sr8;
  const float* asrc = A + (size_t)(m0 + w*32 + sr8)*HH + sc*4;

  #pragma unroll
  for (int i = 0; i < 4; i++) gload_ldsv(asrc + (size_t)i*8*HH, &As[0][(w*32 + i*8)*32]);
  #pragma unroll
  for (int i = 0; i < 2; i++) gload_ldsv(wtp + i*512, &Ws[0][w*1024 + i*512]);
  __syncthreads();

  for (int t = 0; t < 64; t++){
    const int cur = t & 1;
    if (t < 63){
      #pragma unroll
      for (int i = 0; i < 4; i++)
        gload_ldsv(asrc + (size_t)i*8*HH + (t+1)*32, &As[cur^1][(w*32 + i*8)*32]);
      #pragma unroll
      for (int i = 0; i < 2; i++)
        gload_ldsv(wtp + (size_t)(t+1)*8192 + i*512, &Ws[cur^1][w*1024 + i*512]);
    }
    const float* At = As[cur];
    f16x8 ah[2], al[2];
    #pragma unroll
    for (int i = 0; i < 2; i++){
      const int tr = w*32 + i*16 + lr;
      const int pxx = lr & 7;
      float4 fa = *(const float4*)&At[tr*32 + (((2*q)   ^ pxx) << 2)];
      float4 fb = *(const float4*)&At[tr*32 + (((2*q+1) ^ pxx) << 2)];
      float av[8] = {fa.x,fa.y,fa.z,fa.w, fb.x,fb.y,fb.z,fb.w};
      #pragma unroll
      for (int e = 0; e < 8; e++){
        _Float16 h = (_Float16)av[e];
        ah[i][e] = h; al[i][e] = (_Float16)(av[e] - (float)h);
      }
    }
    const unsigned short* Wc = Ws[cur];
    __builtin_amdgcn_s_setprio(1);
    #pragma unroll
    for (int jp = 0; jp < 8; jp++){
      f16x8 b0, b1;
      __builtin_memcpy(&b0, Wc + (2*jp)*512 + rpB, 16);
      __builtin_memcpy(&b1, Wc + (2*jp+1)*512 + rpB, 16);
      acc[0][2*jp]   = __builtin_amdgcn_mfma_f32_16x16x32_f16(ah[0], b0, acc[0][2*jp],   0, 0, 0);
      acc[1][2*jp]   = __builtin_amdgcn_mfma_f32_16x16x32_f16(ah[1], b0, acc[1][2*jp],   0, 0, 0);
      acc[0][2*jp+1] = __builtin_amdgcn_mfma_f32_16x16x32_f16(ah[0], b1, acc[0][2*jp+1], 0, 0, 0);
      acc[1][2*jp+1] = __builtin_amdgcn_mfma_f32_16x16x32_f16(ah[1], b1, acc[1][2*jp+1], 0, 0, 0);
      acc[0][2*jp]   = __builtin_amdgcn_mfma_f32_16x16x32_f16(al[0], b0, acc[0][2*jp],   0, 0, 0);
      acc[1][2*jp]   = __builtin_amdgcn_mfma_f32_16x16x32_f16(al[1], b0, acc[1][2*jp],   0, 0, 0);
      acc[0][2*jp+1] = __builtin_amdgcn_mfma_f32_16x16x32_f16(al[0], b1, acc[0][2*jp+1], 0, 0, 0);
      acc[1][2*jp+1] = __builtin_amdgcn_mfma_f32_16x16x32_f16(al[1], b1, acc[1][2*jp+1], 0, 0, 0);
    }
    __builtin_amdgcn_s_setprio(0);
    __syncthreads();
  }

  const bool isP = (nb >= 2);
  const float* b1p = isP ? bp1 : bg1;
  const float* w2 = isP ? Wp2 : Wg2;
  float* zt = isP ? z2 : z1;
  const int nbl = nb*256 - (isP ? HQ : 0);
  float s[2][4] = {};
  #pragma unroll
  for (int j = 0; j < 16; j++){
    const int n = nbl + j*16 + lr;
    const float bb = b1p[n], ww = w2[n];
    #pragma unroll
    for (int i = 0; i < 2; i++)
      #pragma unroll
      for (int r = 0; r < 4; r++)
        s[i][r] += fmaxf(acc[i][j][r] + bb, 0.f) * ww;
  }
  #pragma unroll
  for (int mk = 1; mk < 16; mk <<= 1)
    #pragma unroll
    for (int i = 0; i < 2; i++)
      #pragma unroll
      for (int r = 0; r < 4; r++)
        s[i][r] += __shfl_xor(s[i][r], mk);
  if (lr == 0){
    #pragma unroll
    for (int i = 0; i < 2; i++)
      #pragma unroll
      for (int r = 0; r < 4; r++)
        atomicAdd(&zt[m0 + w*32 + i*16 + q*4 + r], s[i][r]);
  }
}

// K7: fused sims + masked max/argmax. NEW: 64 t-rows per wave (afr[4][8]) —
// doubles MFMAs per LDS byte read (same LDS-BW-bound cure as k_gp). 256-row
// t-blocks -> 512 blocks; XCD grouping (xcd = ns&7) preserved. ~196 VGPR ->
// 2 waves/SIMD (no launch_bounds min-wave cap, avoid forced spill).
__global__ __launch_bounds__(256) void k_sims(const unsigned short* __restrict__ obf,
    const unsigned short* __restrict__ bbf, const unsigned char* __restrict__ mask,
    float* __restrict__ pmax, int* __restrict__ pidx){
  const int bid = blockIdx.x;                // 0..511
  const int u = bid >> 3;                    // 0..63
  const int ns = (bid & 7) + ((u >> 4) << 3);   // 0..31; xcd = ns&7
  const int t0 = (u & 15) * 256;
  const int nbase0 = ns * (NN/32);           // 1024-row slice
  const int tid = threadIdx.x;
  const int w = tid >> 6, lane = tid & 63;
  const int lr = lane & 15, q = lane >> 4;
  __shared__ __align__(16) unsigned short bt[2][32*256];   // 2 x 16 KB
  __shared__ __align__(16) unsigned char am[1024];
  const int srow = lane >> 5;
  const int sp   = lane & 31;

  ((unsigned int*)am)[tid] = ((const unsigned int*)(mask + nbase0))[tid];

  #pragma unroll
  for (int i = 0; i < 4; i++){
    const int row = (i*4 + w)*2 + srow;
    const unsigned short* src = bbf + (size_t)(nbase0 + row)*DD + ((sp ^ (row & 31)) << 3);
    gload_ldsv(src, &bt[0][(i*4 + w)*512]);
  }
  bf16x8 afr[4][8];
  #pragma unroll
  for (int i = 0; i < 4; i++){
    const unsigned short* ap = obf + (size_t)(t0 + w*64 + i*16 + lr)*DD + q*8;
    #pragma unroll
    for (int ks = 0; ks < 8; ks++)
      afr[i][ks] = as_bf16x8(*(const uint4*)(ap + ks*32));
  }
  __syncthreads();

  float vmax[4][4]; int vidx[4][4];
  #pragma unroll
  for (int i = 0; i < 4; i++)
    #pragma unroll
    for (int r = 0; r < 4; r++){ vmax[i][r] = -INFINITY; vidx[i][r] = -1; }

  int cur = 0;
  for (int it = 0; it < 32; it++){
    const int nl = it*32;
    if (it < 31){
      #pragma unroll
      for (int i = 0; i < 4; i++){
        const int row = (i*4 + w)*2 + srow;
        const unsigned short* src = bbf + (size_t)(nbase0 + nl + 32 + row)*DD + ((sp ^ (row & 31)) << 3);
        gload_ldsv(src, &bt[cur^1][(i*4 + w)*512]);
      }
    }
    const unsigned short* btc = bt[cur];
    #pragma unroll
    for (int sub = 0; sub < 2; sub++){
      const int rowi = sub*16 + lr;
      const bool act = (am[nl + rowi] != 0);
      const unsigned short* bp = btc + rowi*256;
      f32x4 acc[4] = {};
      __builtin_amdgcn_s_setprio(1);
      #pragma unroll
      for (int ks = 0; ks < 8; ks++){
        const int p = (q + ks*4) ^ rowi;
        bf16x8 bfr = as_bf16x8(*(const uint4*)(bp + (p & 31)*8));
        #pragma unroll
        for (int i = 0; i < 4; i++)
          acc[i] = __builtin_amdgcn_mfma_f32_16x16x32_bf16(afr[i][ks], bfr, acc[i], 0, 0, 0);
      }
      __builtin_amdgcn_s_setprio(0);
      if (act){
        const int n = nbase0 + nl + rowi;
        #pragma unroll
        for (int i = 0; i < 4; i++)
          #pragma unroll
          for (int r = 0; r < 4; r++)
            if (acc[i][r] > vmax[i][r]){ vmax[i][r] = acc[i][r]; vidx[i][r] = n; }
      }
    }
    __syncthreads();
    cur ^= 1;
  }
  #pragma unroll
  for (int mk = 1; mk < 16; mk <<= 1){
    #pragma unroll
    for (int i = 0; i < 4; i++)
      #pragma unroll
      for (int r = 0; r < 4; r++){
        float om = __shfl_xor(vmax[i][r], mk);
        int   oi = __shfl_xor(vidx[i][r], mk);
        if (om > vmax[i][r] || (om == vmax[i][r] && (unsigned)oi < (unsigned)vidx[i][r])){
          vmax[i][r] = om; vidx[i][r] = oi;
        }
      }
  }
  if (lr == 0){
    #pragma unroll
    for (int i = 0; i < 4; i++)
      #pragma unroll
      for (int r = 0; r < 4; r++){
        const int t = t0 + w*64 + i*16 + q*4 + r;
        pmax[ns*TT + t] = vmax[i][r];
        pidx[ns*TT + t] = vidx[i][r];
      }
  }
}

// K8: combine n-splits + match logic
__global__ __launch_bounds__(256) void k_combine(const float* __restrict__ pmax,
    const int* __restrict__ pidx, const float* __restrict__ out3,
    const int* __restrict__ flag, float* __restrict__ out1, float* __restrict__ out2){
  const int t = blockIdx.x*256 + threadIdx.x;
  float best = -INFINITY; int bi = -1;
  #pragma unroll
  for (int s = 0; s < 32; s++){
    float m = pmax[s*TT + t];
    if (m > best){ best = m; bi = pidx[s*TT + t]; }
  }
  const bool anyA = (flag[0] != 0);
  const bool mf = out3[t] != 0.f;
  const bool matched = mf && anyA && (best > 0.5f);
  out1[t] = matched ? best : 0.f;
  out2[t] = matched ? (float)bi : -1.f;
}

extern "C" void kernel_launch(void* const* d_in, const int* in_sizes, int n_in,
                              void* d_out, int out_size, void* d_ws, size_t ws_size,
                              hipStream_t stream) {
  const float* hidden = (const float*)d_in[0];
  const float* beliefs = (const float*)d_in[1];
  const unsigned char* amask = (const unsigned char*)d_in[2];
  const float* W_obs = (const float*)d_in[3];
  const float* W_g1 = (const float*)d_in[4];
  const float* b_g1 = (const float*)d_in[5];
  const float* W_g2 = (const float*)d_in[6];
  const float* b_g2 = (const float*)d_in[7];
  const float* W_p1 = (const float*)d_in[8];
  const float* b_p1 = (const float*)d_in[9];
  const float* W_p2 = (const float*)d_in[10];
  const float* b_p2 = (const float*)d_in[11];

  char* ws = (char*)d_ws;
  const size_t HMB_OFF  = 0;                 // 16777216
  const size_t WSW_OFF  = 16777216;          // 4194304 (swizzled)
  const size_t WOB_OFF  = 20971520;          // 1048576
  const size_t Z1_OFF   = 26214400;          // 65536
  const size_t Z2_OFF   = 26279936;          // 65536
  const size_t FLAG_OFF = 26345472;          // 256  (contiguous with z1/z2 for zeroing)
  const size_t OBF_OFF  = 26362112;          // 2097152
  const size_t BBF_OFF  = 28459264;          // 16777216
  const size_t PMAX_OFF = 45236480;          // 524288
  const size_t PIDX_OFF = 45760768;          // 524288    end ~46.3 MB

  unsigned short* hmb = (unsigned short*)(ws + HMB_OFF);
  unsigned short* Wsw = (unsigned short*)(ws + WSW_OFF);
  unsigned short* wob = (unsigned short*)(ws + WOB_OFF);
  float* z1  = (float*)(ws + Z1_OFF);
  float* z2  = (float*)(ws + Z2_OFF);
  int*   flg = (int*)(ws + FLAG_OFF);
  unsigned short* obf = (unsigned short*)(ws + OBF_OFF);
  unsigned short* bbf = (unsigned short*)(ws + BBF_OFF);
  float* pmax = (float*)(ws + PMAX_OFF);
  int*   pidx = (int*)(ws + PIDX_OFF);

  float* out0 = (float*)d_out;            // [T,D] obs_beliefs
  float* out1 = out0 + (size_t)TT*DD;     // [T] sims_out
  float* out2 = out1 + TT;                // [T] slots
  float* out3 = out2 + TT;                // [T] meaningful

  k_prep    <<<PREP_GRID, 256, 0, stream>>>(hidden, hmb, W_g1, W_p1, Wsw,
                W_obs, wob, beliefs, bbf, (unsigned int*)z1);
  k_gp      <<<256, 512, 0, stream>>>(hidden, Wsw, b_g1, b_p1, W_g2, W_p2, z1, z2);
  k_obs     <<<64 + NN/256, 256, 0, stream>>>(hmb, wob, z1, z2, b_g2, b_p2,
                out0, out3, obf, amask, flg);
  k_sims    <<<512, 256, 0, stream>>>(obf, bbf, amask, pmax, pidx);
  k_combine <<<TT/256, 256, 0, stream>>>(pmax, pidx, out3, flg, out1, out2);
}

// Round 8
// 461.459 us; speedup vs baseline: 1.1363x; 1.1363x over previous
//
#include <hip/hip_runtime.h>
#include <hip/hip_bf16.h>
#include <math.h>

#define TB 4
#define TT 4096
#define HH 2048
#define DD 256
#define NN 32768
#define HQ 512
#define MM (TB*TT)

typedef __attribute__((ext_vector_type(8))) short bf16x8;
typedef __attribute__((ext_vector_type(8))) _Float16 f16x8;
typedef __attribute__((ext_vector_type(4))) float f32x4;

__device__ inline unsigned short f2bf(float x){
  __hip_bfloat16 h = __float2bfloat16(x);
  return *reinterpret_cast<unsigned short*>(&h);
}

__device__ inline unsigned short f2h(float x){
  _Float16 h = (_Float16)x;
  unsigned short u; __builtin_memcpy(&u, &h, 2); return u;
}

__device__ inline bf16x8 as_bf16x8(uint4 u){ bf16x8 r; __builtin_memcpy(&r,&u,16); return r; }

// async global->LDS DMA, 16B per lane. LDS dest = wave-uniform base + lane*16;
// global source is per-lane.
__device__ __forceinline__ void gload_ldsv(const void* g, void* l){
  __builtin_amdgcn_global_load_lds(
      (const __attribute__((address_space(1))) unsigned int*)g,
      (__attribute__((address_space(3))) unsigned int*)l, 16, 0, 0);
}

// K_prep: fused preprocessing — batch-mean (8192) + cvt_w (1024) + cvt_wobs
// (512) + beliefs-normalize (8192) + z1/z2/flag zero (129) + om zero (1024).
#define PREP_MEAN 8192
#define PREP_CVTW 1024
#define PREP_WOBS 512
#define PREP_BEL  8192
#define PREP_ZERO 129
#define PREP_ZOM  1024
#define PREP_GRID (PREP_MEAN+PREP_CVTW+PREP_WOBS+PREP_BEL+PREP_ZERO+PREP_ZOM)
__global__ __launch_bounds__(256) void k_prep(
    const float* __restrict__ h, unsigned short* __restrict__ hmb,
    const float* __restrict__ Wg1, const float* __restrict__ Wp1,
    unsigned short* __restrict__ Wsw,
    const float* __restrict__ Wobs, unsigned short* __restrict__ wob,
    const float* __restrict__ bel, unsigned short* __restrict__ bbf,
    unsigned int* __restrict__ zbase, float* __restrict__ om){
  const int b = blockIdx.x;
  if (b < PREP_MEAN){
    const size_t i = (size_t)b*256 + threadIdx.x;
    const size_t TH4 = (size_t)TT*HH/4;
    const float4* p = (const float4*)h;
    float4 v0 = p[i], v1 = p[i+TH4], v2 = p[i+2*TH4], v3 = p[i+3*TH4];
    float4 m;
    m.x = 0.25f*(v0.x+v1.x+v2.x+v3.x);
    m.y = 0.25f*(v0.y+v1.y+v2.y+v3.y);
    m.z = 0.25f*(v0.z+v1.z+v2.z+v3.z);
    m.w = 0.25f*(v0.w+v1.w+v2.w+v3.w);
    ushort4 o; o.x = f2bf(m.x); o.y = f2bf(m.y); o.z = f2bf(m.z); o.w = f2bf(m.w);
    *(ushort4*)(hmb + i*4) = o;
  } else if (b < PREP_MEAN + PREP_CVTW){
    const int id = (b - PREP_MEAN)*256 + threadIdx.x;
    const int n = id >> 8;
    const int cg = id & 255;
    const int k = cg*8;
    const int kc = cg >> 2;
    const int c8 = cg & 3;
    const float* src = (n < HQ) ? (Wg1 + (size_t)n*HH + k) : (Wp1 + (size_t)(n-HQ)*HH + k);
    float4 v0 = *(const float4*)src;
    float4 v1 = *(const float4*)(src + 4);
    unsigned short o[8] = {f2h(v0.x),f2h(v0.y),f2h(v0.z),f2h(v0.w),
                           f2h(v1.x),f2h(v1.y),f2h(v1.z),f2h(v1.w)};
    const int nb = n >> 8, r = n & 255;
    const int s = (r & 3) ^ ((r >> 2) & 3);
    unsigned short* dst = Wsw + ((size_t)(nb*64 + kc))*8192 + r*32 + ((c8 ^ s) << 3);
    __builtin_memcpy(dst, o, 16);
  } else if (b < PREP_MEAN + PREP_CVTW + PREP_WOBS){
    const int idx4 = (b - PREP_MEAN - PREP_CVTW)*256 + threadIdx.x;
    float4 v = *(const float4*)(Wobs + (size_t)idx4*4);
    ushort4 o; o.x = f2bf(v.x); o.y = f2bf(v.y); o.z = f2bf(v.z); o.w = f2bf(v.w);
    *(ushort4*)(wob + (size_t)idx4*4) = o;
  } else if (b < PREP_MEAN + PREP_CVTW + PREP_WOBS + PREP_BEL){
    const int bb = b - (PREP_MEAN + PREP_CVTW + PREP_WOBS);
    const int n = (bb*256 + threadIdx.x) >> 6;
    const int lane = threadIdx.x & 63;
    const float4 v = *(const float4*)(bel + (size_t)n*DD + lane*4);
    float s = v.x*v.x + v.y*v.y + v.z*v.z + v.w*v.w;
    #pragma unroll
    for (int m = 1; m < 64; m <<= 1) s += __shfl_xor(s, m);
    const float inv = 1.f / fmaxf(sqrtf(s), 1e-8f);
    ushort4 o;
    o.x = f2bf(v.x*inv); o.y = f2bf(v.y*inv); o.z = f2bf(v.z*inv); o.w = f2bf(v.w*inv);
    *(ushort4*)(bbf + (size_t)n*DD + lane*4) = o;
  } else if (b < PREP_MEAN + PREP_CVTW + PREP_WOBS + PREP_BEL + PREP_ZERO){
    const int idx = (b - (PREP_MEAN + PREP_CVTW + PREP_WOBS + PREP_BEL))*256 + threadIdx.x;
    if (idx < 32832) zbase[idx] = 0;
  } else {
    const int idx = (b - (PREP_MEAN + PREP_CVTW + PREP_WOBS + PREP_BEL + PREP_ZERO))*256
                    + threadIdx.x;
    float4 z = {0.f, 0.f, 0.f, 0.f};
    *(float4*)(om + (size_t)idx*4) = z;
  }
}

// K_obsp: obs_mean GEMM, K-split by 4 -> 256 blocks (whole chip, vs the old
// 64-block/64-CU version with zero overlap partners). BM=64, BN=256, 16 steps
// of the full-DMA double-buffer template; partials accumulate into om via
// atomicAdd (om zeroed in k_prep).
__global__ __launch_bounds__(256) void k_obsp(const unsigned short* __restrict__ A,
    const unsigned short* __restrict__ Bw, float* __restrict__ om){
  const int bid = blockIdx.x;          // 0..255
  const int m0 = (bid & 63) * 64;
  const int k0 = (bid >> 6) * 512;
  const int tid = threadIdx.x;
  const int w = tid>>6, lane = tid&63, lr = lane&15, q = lane>>4;
  __shared__ __align__(16) unsigned short As[2][64*32];    // 2 x 4 KB
  __shared__ __align__(16) unsigned short Bs[2][256*32];   // 2 x 16 KB
  f32x4 acc[16] = {};
  const int srow = lane >> 2, sch = (lane & 3) ^ (srow & 3);
  const unsigned short* asrc = A + (size_t)(m0 + w*16 + srow)*HH + k0 + sch*8;

  gload_ldsv(asrc, &As[0][w*16*32]);
  #pragma unroll
  for (int i = 0; i < 4; i++){
    const unsigned short* bsrc = Bw + (size_t)((i*4 + w)*16 + srow)*HH + k0 + sch*8;
    gload_ldsv(bsrc, &Bs[0][(i*4 + w)*16*32]);
  }
  __syncthreads();
  const int px = (q ^ (lr & 3)) << 3;
  for (int t = 0; t < 16; t++){
    const int cur = t & 1;
    if (t < 15){
      const int ko = (t+1)*32;
      gload_ldsv(asrc + ko, &As[cur^1][w*16*32]);
      #pragma unroll
      for (int i = 0; i < 4; i++){
        const unsigned short* bsrc = Bw + (size_t)((i*4 + w)*16 + srow)*HH + k0 + ko + sch*8;
        gload_ldsv(bsrc, &Bs[cur^1][(i*4 + w)*16*32]);
      }
    }
    bf16x8 a = as_bf16x8(*(const uint4*)&As[cur][(w*16 + lr)*32 + px]);
    #pragma unroll
    for (int j = 0; j < 16; j++){
      bf16x8 bb = as_bf16x8(*(const uint4*)&Bs[cur][(j*16 + lr)*32 + px]);
      acc[j] = __builtin_amdgcn_mfma_f32_16x16x32_bf16(a, bb, acc[j], 0, 0, 0);
    }
    __syncthreads();
  }
  #pragma unroll
  for (int j = 0; j < 16; j++)
    #pragma unroll
    for (int r = 0; r < 4; r++)
      atomicAdd(&om[(size_t)(m0 + w*16 + q*4 + r)*DD + j*16 + lr], acc[j][r]);
}

// K4: gate/prec layer1 — EXACT round-6 code (measured 112.1 µs, MfmaUtil 55%).
// BM=128, 256 threads, 2 blocks/CU (the barrier-overlap partner r7 proved
// essential), full-DMA double-buffer, j-pair MFMA order, XCD-grouped grid.
__global__ __launch_bounds__(256, 2) void k_gp(const float* __restrict__ A,
    const unsigned short* __restrict__ Wsw,
    const float* __restrict__ bg1, const float* __restrict__ bp1,
    const float* __restrict__ Wg2, const float* __restrict__ Wp2,
    float* __restrict__ z1, float* __restrict__ z2){
  const int bid = blockIdx.x;
  const int nb = (bid >> 3) & 3;
  const int my = (bid & 7) + ((bid >> 5) << 3);
  const int m0 = my*128;
  const int tid = threadIdx.x;
  const int w = tid>>6, lane = tid&63, lr = lane&15, q = lane>>4;
  __shared__ __align__(16) unsigned short Ws[2][8192];   // 2 x 16 KB W tiles
  __shared__ __align__(16) float As[2][4096];            // 2 x 16 KB A tiles
  f32x4 acc[2][16] = {};

  const unsigned short* wt = Wsw + (size_t)nb*64*8192 + w*2048 + lane*8;
  const int rpB = lr*32 + ((q ^ ((lr & 3) ^ ((lr >> 2) & 3))) << 3);
  const int sr8 = lane >> 3;
  const int sc  = (lane & 7) ^ sr8;
  const float* asrc = A + (size_t)(m0 + w*32 + sr8)*HH + sc*4;

  #pragma unroll
  for (int i = 0; i < 4; i++) gload_ldsv(asrc + (size_t)i*8*HH, &As[0][(w*32 + i*8)*32]);
  #pragma unroll
  for (int i = 0; i < 4; i++) gload_ldsv(wt + i*512, &Ws[0][w*2048 + i*512]);
  __syncthreads();

  for (int t = 0; t < 64; t++){
    const int cur = t & 1;
    if (t < 63){
      #pragma unroll
      for (int i = 0; i < 4; i++)
        gload_ldsv(asrc + (size_t)i*8*HH + (t+1)*32, &As[cur^1][(w*32 + i*8)*32]);
      #pragma unroll
      for (int i = 0; i < 4; i++)
        gload_ldsv(wt + (size_t)(t+1)*8192 + i*512, &Ws[cur^1][w*2048 + i*512]);
    }
    const float* At = As[cur];
    f16x8 ah[2], al[2];
    #pragma unroll
    for (int i = 0; i < 2; i++){
      const int tr = w*32 + i*16 + lr;
      const int pxx = lr & 7;
      float4 fa = *(const float4*)&At[tr*32 + (((2*q)   ^ pxx) << 2)];
      float4 fb = *(const float4*)&At[tr*32 + (((2*q+1) ^ pxx) << 2)];
      float av[8] = {fa.x,fa.y,fa.z,fa.w, fb.x,fb.y,fb.z,fb.w};
      #pragma unroll
      for (int e = 0; e < 8; e++){
        _Float16 h = (_Float16)av[e];
        ah[i][e] = h; al[i][e] = (_Float16)(av[e] - (float)h);
      }
    }
    const unsigned short* Wc = Ws[cur];
    __builtin_amdgcn_s_setprio(1);
    #pragma unroll
    for (int jp = 0; jp < 8; jp++){
      f16x8 b0, b1;
      __builtin_memcpy(&b0, Wc + (2*jp)*512 + rpB, 16);
      __builtin_memcpy(&b1, Wc + (2*jp+1)*512 + rpB, 16);
      acc[0][2*jp]   = __builtin_amdgcn_mfma_f32_16x16x32_f16(ah[0], b0, acc[0][2*jp],   0, 0, 0);
      acc[1][2*jp]   = __builtin_amdgcn_mfma_f32_16x16x32_f16(ah[1], b0, acc[1][2*jp],   0, 0, 0);
      acc[0][2*jp+1] = __builtin_amdgcn_mfma_f32_16x16x32_f16(ah[0], b1, acc[0][2*jp+1], 0, 0, 0);
      acc[1][2*jp+1] = __builtin_amdgcn_mfma_f32_16x16x32_f16(ah[1], b1, acc[1][2*jp+1], 0, 0, 0);
      acc[0][2*jp]   = __builtin_amdgcn_mfma_f32_16x16x32_f16(al[0], b0, acc[0][2*jp],   0, 0, 0);
      acc[1][2*jp]   = __builtin_amdgcn_mfma_f32_16x16x32_f16(al[1], b0, acc[1][2*jp],   0, 0, 0);
      acc[0][2*jp+1] = __builtin_amdgcn_mfma_f32_16x16x32_f16(al[0], b1, acc[0][2*jp+1], 0, 0, 0);
      acc[1][2*jp+1] = __builtin_amdgcn_mfma_f32_16x16x32_f16(al[1], b1, acc[1][2*jp+1], 0, 0, 0);
    }
    __builtin_amdgcn_s_setprio(0);
    __syncthreads();
  }

  const bool isP = (nb >= 2);
  const float* b1p = isP ? bp1 : bg1;
  const float* w2 = isP ? Wp2 : Wg2;
  float* zt = isP ? z2 : z1;
  const int nbl = nb*256 - (isP ? HQ : 0);
  float s[2][4] = {};
  #pragma unroll
  for (int j = 0; j < 16; j++){
    const int n = nbl + j*16 + lr;
    const float bb = b1p[n], ww = w2[n];
    #pragma unroll
    for (int i = 0; i < 2; i++)
      #pragma unroll
      for (int r = 0; r < 4; r++)
        s[i][r] += fmaxf(acc[i][j][r] + bb, 0.f) * ww;
  }
  #pragma unroll
  for (int mk = 1; mk < 16; mk <<= 1)
    #pragma unroll
    for (int i = 0; i < 2; i++)
      #pragma unroll
      for (int r = 0; r < 4; r++)
        s[i][r] += __shfl_xor(s[i][r], mk);
  if (lr == 0){
    #pragma unroll
    for (int i = 0; i < 2; i++)
      #pragma unroll
      for (int r = 0; r < 4; r++)
        atomicAdd(&zt[m0 + w*32 + i*16 + q*4 + r], s[i][r]);
  }
}

// K_fin: per-t finalize (proven r5 k_obs_fin body) + any-active blocks.
// blocks 0..1023: 4 t per block, one wave per t. blocks 1024..1151: any.
__global__ __launch_bounds__(256) void k_fin(const float* __restrict__ om,
    const float* __restrict__ z1, const float* __restrict__ z2,
    const float* __restrict__ bg2, const float* __restrict__ bp2,
    float* __restrict__ out0, float* __restrict__ out3,
    unsigned short* __restrict__ obf,
    const unsigned char* __restrict__ mask, int* __restrict__ flag){
  const int blk = blockIdx.x;
  const int tid = threadIdx.x;
  if (blk >= 1024){
    const int i = (blk - 1024)*256 + tid;
    const int any = (mask[i] != 0) ? 1 : 0;
    if (__ballot(any)){
      if ((tid & 63) == 0) atomicOr(flag, 1);
    }
    return;
  }
  const int w = tid >> 6, lane = tid & 63;
  const int t = blk*4 + w;
  float pm = 0.f;
  if (lane < TB){
    float a = z1[lane*TT + t] + bg2[0];
    float b = z2[lane*TT + t] + bp2[0];
    float gate = 1.f/(1.f + expf(-a));
    float sp = (b > 0.f) ? (b + log1pf(expf(-b))) : log1pf(expf(b));
    pm = gate * sp;
  }
  #pragma unroll
  for (int m = 1; m < 4; m <<= 1) pm += __shfl_xor(pm, m);
  pm = __shfl(pm, 0) * 0.25f;
  float4 x = *(const float4*)(om + (size_t)t*DD + lane*4);
  float ss = x.x*x.x + x.y*x.y + x.z*x.z + x.w*x.w;
  #pragma unroll
  for (int m = 1; m < 64; m <<= 1) ss += __shfl_xor(ss, m);
  const float nrm = sqrtf(ss);
  const float sc = pm / fmaxf(nrm, 1e-8f);
  float4 ob = {x.x*sc, x.y*sc, x.z*sc, x.w*sc};
  *(float4*)(out0 + (size_t)t*DD + lane*4) = ob;
  float s2 = ob.x*ob.x + ob.y*ob.y + ob.z*ob.z + ob.w*ob.w;
  #pragma unroll
  for (int m = 1; m < 64; m <<= 1) s2 += __shfl_xor(s2, m);
  const float r2 = sqrtf(s2);
  if (lane == 0) out3[t] = (r2 > 0.05f) ? 1.f : 0.f;
  const float inv2 = 1.f / fmaxf(r2, 1e-8f);
  ushort4 o = {f2bf(ob.x*inv2), f2bf(ob.y*inv2), f2bf(ob.z*inv2), f2bf(ob.w*inv2)};
  *(ushort4*)(obf + (size_t)t*DD + lane*4) = o;
}

// K7: fused sims + masked max/argmax — round-7 version (64 t-rows/wave,
// inferred −28 µs), XCD-grouped (xcd = ns&7), async DMA double-buffer.
__global__ __launch_bounds__(256) void k_sims(const unsigned short* __restrict__ obf,
    const unsigned short* __restrict__ bbf, const unsigned char* __restrict__ mask,
    float* __restrict__ pmax, int* __restrict__ pidx){
  const int bid = blockIdx.x;                // 0..511
  const int u = bid >> 3;                    // 0..63
  const int ns = (bid & 7) + ((u >> 4) << 3);   // 0..31; xcd = ns&7
  const int t0 = (u & 15) * 256;
  const int nbase0 = ns * (NN/32);           // 1024-row slice
  const int tid = threadIdx.x;
  const int w = tid >> 6, lane = tid & 63;
  const int lr = lane & 15, q = lane >> 4;
  __shared__ __align__(16) unsigned short bt[2][32*256];   // 2 x 16 KB
  __shared__ __align__(16) unsigned char am[1024];
  const int srow = lane >> 5;
  const int sp   = lane & 31;

  ((unsigned int*)am)[tid] = ((const unsigned int*)(mask + nbase0))[tid];

  #pragma unroll
  for (int i = 0; i < 4; i++){
    const int row = (i*4 + w)*2 + srow;
    const unsigned short* src = bbf + (size_t)(nbase0 + row)*DD + ((sp ^ (row & 31)) << 3);
    gload_ldsv(src, &bt[0][(i*4 + w)*512]);
  }
  bf16x8 afr[4][8];
  #pragma unroll
  for (int i = 0; i < 4; i++){
    const unsigned short* ap = obf + (size_t)(t0 + w*64 + i*16 + lr)*DD + q*8;
    #pragma unroll
    for (int ks = 0; ks < 8; ks++)
      afr[i][ks] = as_bf16x8(*(const uint4*)(ap + ks*32));
  }
  __syncthreads();

  float vmax[4][4]; int vidx[4][4];
  #pragma unroll
  for (int i = 0; i < 4; i++)
    #pragma unroll
    for (int r = 0; r < 4; r++){ vmax[i][r] = -INFINITY; vidx[i][r] = -1; }

  int cur = 0;
  for (int it = 0; it < 32; it++){
    const int nl = it*32;
    if (it < 31){
      #pragma unroll
      for (int i = 0; i < 4; i++){
        const int row = (i*4 + w)*2 + srow;
        const unsigned short* src = bbf + (size_t)(nbase0 + nl + 32 + row)*DD + ((sp ^ (row & 31)) << 3);
        gload_ldsv(src, &bt[cur^1][(i*4 + w)*512]);
      }
    }
    const unsigned short* btc = bt[cur];
    #pragma unroll
    for (int sub = 0; sub < 2; sub++){
      const int rowi = sub*16 + lr;
      const bool act = (am[nl + rowi] != 0);
      const unsigned short* bp = btc + rowi*256;
      f32x4 acc[4] = {};
      __builtin_amdgcn_s_setprio(1);
      #pragma unroll
      for (int ks = 0; ks < 8; ks++){
        const int p = (q + ks*4) ^ rowi;
        bf16x8 bfr = as_bf16x8(*(const uint4*)(bp + (p & 31)*8));
        #pragma unroll
        for (int i = 0; i < 4; i++)
          acc[i] = __builtin_amdgcn_mfma_f32_16x16x32_bf16(afr[i][ks], bfr, acc[i], 0, 0, 0);
      }
      __builtin_amdgcn_s_setprio(0);
      if (act){
        const int n = nbase0 + nl + rowi;
        #pragma unroll
        for (int i = 0; i < 4; i++)
          #pragma unroll
          for (int r = 0; r < 4; r++)
            if (acc[i][r] > vmax[i][r]){ vmax[i][r] = acc[i][r]; vidx[i][r] = n; }
      }
    }
    __syncthreads();
    cur ^= 1;
  }
  #pragma unroll
  for (int mk = 1; mk < 16; mk <<= 1){
    #pragma unroll
    for (int i = 0; i < 4; i++)
      #pragma unroll
      for (int r = 0; r < 4; r++){
        float om = __shfl_xor(vmax[i][r], mk);
        int   oi = __shfl_xor(vidx[i][r], mk);
        if (om > vmax[i][r] || (om == vmax[i][r] && (unsigned)oi < (unsigned)vidx[i][r])){
          vmax[i][r] = om; vidx[i][r] = oi;
        }
      }
  }
  if (lr == 0){
    #pragma unroll
    for (int i = 0; i < 4; i++)
      #pragma unroll
      for (int r = 0; r < 4; r++){
        const int t = t0 + w*64 + i*16 + q*4 + r;
        pmax[ns*TT + t] = vmax[i][r];
        pidx[ns*TT + t] = vidx[i][r];
      }
  }
}

// K8: combine n-splits + match logic
__global__ __launch_bounds__(256) void k_combine(const float* __restrict__ pmax,
    const int* __restrict__ pidx, const float* __restrict__ out3,
    const int* __restrict__ flag, float* __restrict__ out1, float* __restrict__ out2){
  const int t = blockIdx.x*256 + threadIdx.x;
  float best = -INFINITY; int bi = -1;
  #pragma unroll
  for (int s = 0; s < 32; s++){
    float m = pmax[s*TT + t];
    if (m > best){ best = m; bi = pidx[s*TT + t]; }
  }
  const bool anyA = (flag[0] != 0);
  const bool mf = out3[t] != 0.f;
  const bool matched = mf && anyA && (best > 0.5f);
  out1[t] = matched ? best : 0.f;
  out2[t] = matched ? (float)bi : -1.f;
}

extern "C" void kernel_launch(void* const* d_in, const int* in_sizes, int n_in,
                              void* d_out, int out_size, void* d_ws, size_t ws_size,
                              hipStream_t stream) {
  const float* hidden = (const float*)d_in[0];
  const float* beliefs = (const float*)d_in[1];
  const unsigned char* amask = (const unsigned char*)d_in[2];
  const float* W_obs = (const float*)d_in[3];
  const float* W_g1 = (const float*)d_in[4];
  const float* b_g1 = (const float*)d_in[5];
  const float* W_g2 = (const float*)d_in[6];
  const float* b_g2 = (const float*)d_in[7];
  const float* W_p1 = (const float*)d_in[8];
  const float* b_p1 = (const float*)d_in[9];
  const float* W_p2 = (const float*)d_in[10];
  const float* b_p2 = (const float*)d_in[11];

  char* ws = (char*)d_ws;
  const size_t HMB_OFF  = 0;                 // 16777216
  const size_t WSW_OFF  = 16777216;          // 4194304 (swizzled)
  const size_t WOB_OFF  = 20971520;          // 1048576
  const size_t OM_OFF   = 22020096;          // 4194304 (f32 obs_mean partials)
  const size_t Z1_OFF   = 26214400;          // 65536
  const size_t Z2_OFF   = 26279936;          // 65536
  const size_t FLAG_OFF = 26345472;          // 256  (contiguous with z1/z2 for zeroing)
  const size_t OBF_OFF  = 26362112;          // 2097152
  const size_t BBF_OFF  = 28459264;          // 16777216
  const size_t PMAX_OFF = 45236480;          // 524288
  const size_t PIDX_OFF = 45760768;          // 524288    end ~46.3 MB

  unsigned short* hmb = (unsigned short*)(ws + HMB_OFF);
  unsigned short* Wsw = (unsigned short*)(ws + WSW_OFF);
  unsigned short* wob = (unsigned short*)(ws + WOB_OFF);
  float* om  = (float*)(ws + OM_OFF);
  float* z1  = (float*)(ws + Z1_OFF);
  float* z2  = (float*)(ws + Z2_OFF);
  int*   flg = (int*)(ws + FLAG_OFF);
  unsigned short* obf = (unsigned short*)(ws + OBF_OFF);
  unsigned short* bbf = (unsigned short*)(ws + BBF_OFF);
  float* pmax = (float*)(ws + PMAX_OFF);
  int*   pidx = (int*)(ws + PIDX_OFF);

  float* out0 = (float*)d_out;            // [T,D] obs_beliefs
  float* out1 = out0 + (size_t)TT*DD;     // [T] sims_out
  float* out2 = out1 + TT;                // [T] slots
  float* out3 = out2 + TT;                // [T] meaningful

  k_prep    <<<PREP_GRID, 256, 0, stream>>>(hidden, hmb, W_g1, W_p1, Wsw,
                W_obs, wob, beliefs, bbf, (unsigned int*)z1, om);
  k_obsp    <<<256, 256, 0, stream>>>(hmb, wob, om);
  k_gp      <<<512, 256, 0, stream>>>(hidden, Wsw, b_g1, b_p1, W_g2, W_p2, z1, z2);
  k_fin     <<<1024 + NN/256, 256, 0, stream>>>(om, z1, z2, b_g2, b_p2,
                out0, out3, obf, amask, flg);
  k_sims    <<<512, 256, 0, stream>>>(obf, bbf, amask, pmax, pidx);
  k_combine <<<TT/256, 256, 0, stream>>>(pmax, pidx, out3, flg, out1, out2);
}

// Round 9
// 450.426 us; speedup vs baseline: 1.1641x; 1.0245x over previous
//
#include <hip/hip_runtime.h>
#include <hip/hip_bf16.h>
#include <math.h>

#define TB 4
#define TT 4096
#define HH 2048
#define DD 256
#define NN 32768
#define HQ 512
#define MM (TB*TT)

typedef __attribute__((ext_vector_type(8))) short bf16x8;
typedef __attribute__((ext_vector_type(8))) _Float16 f16x8;
typedef __attribute__((ext_vector_type(4))) float f32x4;

__device__ inline unsigned short f2bf(float x){
  __hip_bfloat16 h = __float2bfloat16(x);
  return *reinterpret_cast<unsigned short*>(&h);
}

__device__ inline unsigned short f2h(float x){
  _Float16 h = (_Float16)x;
  unsigned short u; __builtin_memcpy(&u, &h, 2); return u;
}

__device__ inline bf16x8 as_bf16x8(uint4 u){ bf16x8 r; __builtin_memcpy(&r,&u,16); return r; }

// async global->LDS DMA, 16B per lane. LDS dest = wave-uniform base + lane*16;
// global source is per-lane.
__device__ __forceinline__ void gload_ldsv(const void* g, void* l){
  __builtin_amdgcn_global_load_lds(
      (const __attribute__((address_space(1))) unsigned int*)g,
      (__attribute__((address_space(3))) unsigned int*)l, 16, 0, 0);
}

// K_prep: fused preprocessing — batch-mean (8192) + cvt_w (1024) + cvt_wobs
// (512) + beliefs-normalize (8192) + z1/z2 zero (128) + om zero (1024).
// (any-active flag machinery REMOVED: bi==-1 in combine encodes it.)
#define PREP_MEAN 8192
#define PREP_CVTW 1024
#define PREP_WOBS 512
#define PREP_BEL  8192
#define PREP_ZERO 128
#define PREP_ZOM  1024
#define PREP_GRID (PREP_MEAN+PREP_CVTW+PREP_WOBS+PREP_BEL+PREP_ZERO+PREP_ZOM)
__global__ __launch_bounds__(256) void k_prep(
    const float* __restrict__ h, unsigned short* __restrict__ hmb,
    const float* __restrict__ Wg1, const float* __restrict__ Wp1,
    unsigned short* __restrict__ Wsw,
    const float* __restrict__ Wobs, unsigned short* __restrict__ wob,
    const float* __restrict__ bel, unsigned short* __restrict__ bbf,
    unsigned int* __restrict__ zbase, float* __restrict__ om){
  const int b = blockIdx.x;
  if (b < PREP_MEAN){
    const size_t i = (size_t)b*256 + threadIdx.x;
    const size_t TH4 = (size_t)TT*HH/4;
    const float4* p = (const float4*)h;
    float4 v0 = p[i], v1 = p[i+TH4], v2 = p[i+2*TH4], v3 = p[i+3*TH4];
    float4 m;
    m.x = 0.25f*(v0.x+v1.x+v2.x+v3.x);
    m.y = 0.25f*(v0.y+v1.y+v2.y+v3.y);
    m.z = 0.25f*(v0.z+v1.z+v2.z+v3.z);
    m.w = 0.25f*(v0.w+v1.w+v2.w+v3.w);
    ushort4 o; o.x = f2bf(m.x); o.y = f2bf(m.y); o.z = f2bf(m.z); o.w = f2bf(m.w);
    *(ushort4*)(hmb + i*4) = o;
  } else if (b < PREP_MEAN + PREP_CVTW){
    const int id = (b - PREP_MEAN)*256 + threadIdx.x;
    const int n = id >> 8;
    const int cg = id & 255;
    const int k = cg*8;
    const int kc = cg >> 2;
    const int c8 = cg & 3;
    const float* src = (n < HQ) ? (Wg1 + (size_t)n*HH + k) : (Wp1 + (size_t)(n-HQ)*HH + k);
    float4 v0 = *(const float4*)src;
    float4 v1 = *(const float4*)(src + 4);
    unsigned short o[8] = {f2h(v0.x),f2h(v0.y),f2h(v0.z),f2h(v0.w),
                           f2h(v1.x),f2h(v1.y),f2h(v1.z),f2h(v1.w)};
    const int nb = n >> 8, r = n & 255;
    const int s = (r & 3) ^ ((r >> 2) & 3);
    unsigned short* dst = Wsw + ((size_t)(nb*64 + kc))*8192 + r*32 + ((c8 ^ s) << 3);
    __builtin_memcpy(dst, o, 16);
  } else if (b < PREP_MEAN + PREP_CVTW + PREP_WOBS){
    const int idx4 = (b - PREP_MEAN - PREP_CVTW)*256 + threadIdx.x;
    float4 v = *(const float4*)(Wobs + (size_t)idx4*4);
    ushort4 o; o.x = f2bf(v.x); o.y = f2bf(v.y); o.z = f2bf(v.z); o.w = f2bf(v.w);
    *(ushort4*)(wob + (size_t)idx4*4) = o;
  } else if (b < PREP_MEAN + PREP_CVTW + PREP_WOBS + PREP_BEL){
    const int bb = b - (PREP_MEAN + PREP_CVTW + PREP_WOBS);
    const int n = (bb*256 + threadIdx.x) >> 6;
    const int lane = threadIdx.x & 63;
    const float4 v = *(const float4*)(bel + (size_t)n*DD + lane*4);
    float s = v.x*v.x + v.y*v.y + v.z*v.z + v.w*v.w;
    #pragma unroll
    for (int m = 1; m < 64; m <<= 1) s += __shfl_xor(s, m);
    const float inv = 1.f / fmaxf(sqrtf(s), 1e-8f);
    ushort4 o;
    o.x = f2bf(v.x*inv); o.y = f2bf(v.y*inv); o.z = f2bf(v.z*inv); o.w = f2bf(v.w*inv);
    *(ushort4*)(bbf + (size_t)n*DD + lane*4) = o;
  } else if (b < PREP_MEAN + PREP_CVTW + PREP_WOBS + PREP_BEL + PREP_ZERO){
    const int idx = (b - (PREP_MEAN + PREP_CVTW + PREP_WOBS + PREP_BEL))*256 + threadIdx.x;
    if (idx < 32768) zbase[idx] = 0;   // z1 + z2
  } else {
    const int idx = (b - (PREP_MEAN + PREP_CVTW + PREP_WOBS + PREP_BEL + PREP_ZERO))*256
                    + threadIdx.x;
    float4 z = {0.f, 0.f, 0.f, 0.f};
    *(float4*)(om + (size_t)idx*4) = z;
  }
}

// K_gpo: FUSED obsp (blocks 0..255) + gp (blocks 256..767). Both depend only
// on k_prep outputs; obsp blocks dispatched FIRST so they co-run with gp
// blocks (2 blocks/CU residency) and retire early — obsp's serial time and a
// dispatch boundary disappear. Shared 64KB LDS arena aliased per branch.
// Bodies are the r8-verified obsp and r6/r8-verified gp (115 µs) verbatim.
__global__ __launch_bounds__(256, 2) void k_gpo(const float* __restrict__ A,
    const unsigned short* __restrict__ Wsw,
    const float* __restrict__ bg1, const float* __restrict__ bp1,
    const float* __restrict__ Wg2, const float* __restrict__ Wp2,
    float* __restrict__ z1, float* __restrict__ z2,
    const unsigned short* __restrict__ hmb, const unsigned short* __restrict__ wob,
    float* __restrict__ om){
  __shared__ __align__(16) char smem[65536];
  const int tid = threadIdx.x;
  const int w = tid>>6, lane = tid&63, lr = lane&15, q = lane>>4;

  if (blockIdx.x < 256){
    // ---- obsp: obs_mean partial GEMM, K-split by 4 ----
    const int bid = blockIdx.x;
    const int m0 = (bid & 63) * 64;
    const int k0 = (bid >> 6) * 512;
    unsigned short* AsS = (unsigned short*)smem;            // 2 x 2048 shorts (8KB)
    unsigned short* BsS = (unsigned short*)(smem + 8192);   // 2 x 8192 shorts (32KB)
    f32x4 acc[16] = {};
    const int srow = lane >> 2, sch = (lane & 3) ^ (srow & 3);
    const unsigned short* asrc = hmb + (size_t)(m0 + w*16 + srow)*HH + k0 + sch*8;

    gload_ldsv(asrc, AsS + w*512);
    #pragma unroll
    for (int i = 0; i < 4; i++){
      const unsigned short* bsrc = wob + (size_t)((i*4 + w)*16 + srow)*HH + k0 + sch*8;
      gload_ldsv(bsrc, BsS + (i*4 + w)*512);
    }
    __syncthreads();
    const int px = (q ^ (lr & 3)) << 3;
    for (int t = 0; t < 16; t++){
      const int cur = t & 1;
      if (t < 15){
        const int ko = (t+1)*32;
        gload_ldsv(asrc + ko, AsS + (cur^1)*2048 + w*512);
        #pragma unroll
        for (int i = 0; i < 4; i++){
          const unsigned short* bsrc = wob + (size_t)((i*4 + w)*16 + srow)*HH + k0 + ko + sch*8;
          gload_ldsv(bsrc, BsS + (cur^1)*8192 + (i*4 + w)*512);
        }
      }
      bf16x8 a = as_bf16x8(*(const uint4*)(AsS + cur*2048 + (w*16 + lr)*32 + px));
      #pragma unroll
      for (int j = 0; j < 16; j++){
        bf16x8 bb = as_bf16x8(*(const uint4*)(BsS + cur*8192 + (j*16 + lr)*32 + px));
        acc[j] = __builtin_amdgcn_mfma_f32_16x16x32_bf16(a, bb, acc[j], 0, 0, 0);
      }
      __syncthreads();
    }
    #pragma unroll
    for (int j = 0; j < 16; j++)
      #pragma unroll
      for (int r = 0; r < 4; r++)
        atomicAdd(&om[(size_t)(m0 + w*16 + q*4 + r)*DD + j*16 + lr], acc[j][r]);
    return;
  }

  // ---- gp: gate/prec layer1 (r6 code, measured 115 µs) ----
  const int g = blockIdx.x - 256;
  const int nb = (g >> 3) & 3;
  const int my = (g & 7) + ((g >> 5) << 3);
  const int m0 = my*128;
  unsigned short* Ws = (unsigned short*)smem;     // 2 x 8192 shorts (32KB)
  float* Asf = (float*)(smem + 32768);            // 2 x 4096 floats (32KB)
  f32x4 acc[2][16] = {};

  const unsigned short* wt = Wsw + (size_t)nb*64*8192 + w*2048 + lane*8;
  const int rpB = lr*32 + ((q ^ ((lr & 3) ^ ((lr >> 2) & 3))) << 3);
  const int sr8 = lane >> 3;
  const int sc  = (lane & 7) ^ sr8;
  const float* asrc = A + (size_t)(m0 + w*32 + sr8)*HH + sc*4;

  #pragma unroll
  for (int i = 0; i < 4; i++) gload_ldsv(asrc + (size_t)i*8*HH, Asf + (w*32 + i*8)*32);
  #pragma unroll
  for (int i = 0; i < 4; i++) gload_ldsv(wt + i*512, Ws + w*2048 + i*512);
  __syncthreads();

  for (int t = 0; t < 64; t++){
    const int cur = t & 1;
    if (t < 63){
      #pragma unroll
      for (int i = 0; i < 4; i++)
        gload_ldsv(asrc + (size_t)i*8*HH + (t+1)*32, Asf + (cur^1)*4096 + (w*32 + i*8)*32);
      #pragma unroll
      for (int i = 0; i < 4; i++)
        gload_ldsv(wt + (size_t)(t+1)*8192 + i*512, Ws + (cur^1)*8192 + w*2048 + i*512);
    }
    const float* At = Asf + cur*4096;
    f16x8 ah[2], al[2];
    #pragma unroll
    for (int i = 0; i < 2; i++){
      const int tr = w*32 + i*16 + lr;
      const int pxx = lr & 7;
      float4 fa = *(const float4*)&At[tr*32 + (((2*q)   ^ pxx) << 2)];
      float4 fb = *(const float4*)&At[tr*32 + (((2*q+1) ^ pxx) << 2)];
      float av[8] = {fa.x,fa.y,fa.z,fa.w, fb.x,fb.y,fb.z,fb.w};
      #pragma unroll
      for (int e = 0; e < 8; e++){
        _Float16 h = (_Float16)av[e];
        ah[i][e] = h; al[i][e] = (_Float16)(av[e] - (float)h);
      }
    }
    const unsigned short* Wc = Ws + cur*8192;
    __builtin_amdgcn_s_setprio(1);
    #pragma unroll
    for (int jp = 0; jp < 8; jp++){
      f16x8 b0, b1;
      __builtin_memcpy(&b0, Wc + (2*jp)*512 + rpB, 16);
      __builtin_memcpy(&b1, Wc + (2*jp+1)*512 + rpB, 16);
      acc[0][2*jp]   = __builtin_amdgcn_mfma_f32_16x16x32_f16(ah[0], b0, acc[0][2*jp],   0, 0, 0);
      acc[1][2*jp]   = __builtin_amdgcn_mfma_f32_16x16x32_f16(ah[1], b0, acc[1][2*jp],   0, 0, 0);
      acc[0][2*jp+1] = __builtin_amdgcn_mfma_f32_16x16x32_f16(ah[0], b1, acc[0][2*jp+1], 0, 0, 0);
      acc[1][2*jp+1] = __builtin_amdgcn_mfma_f32_16x16x32_f16(ah[1], b1, acc[1][2*jp+1], 0, 0, 0);
      acc[0][2*jp]   = __builtin_amdgcn_mfma_f32_16x16x32_f16(al[0], b0, acc[0][2*jp],   0, 0, 0);
      acc[1][2*jp]   = __builtin_amdgcn_mfma_f32_16x16x32_f16(al[1], b0, acc[1][2*jp],   0, 0, 0);
      acc[0][2*jp+1] = __builtin_amdgcn_mfma_f32_16x16x32_f16(al[0], b1, acc[0][2*jp+1], 0, 0, 0);
      acc[1][2*jp+1] = __builtin_amdgcn_mfma_f32_16x16x32_f16(al[1], b1, acc[1][2*jp+1], 0, 0, 0);
    }
    __builtin_amdgcn_s_setprio(0);
    __syncthreads();
  }

  const bool isP = (nb >= 2);
  const float* b1p = isP ? bp1 : bg1;
  const float* w2 = isP ? Wp2 : Wg2;
  float* zt = isP ? z2 : z1;
  const int nbl = nb*256 - (isP ? HQ : 0);
  float s[2][4] = {};
  #pragma unroll
  for (int j = 0; j < 16; j++){
    const int n = nbl + j*16 + lr;
    const float bb = b1p[n], ww = w2[n];
    #pragma unroll
    for (int i = 0; i < 2; i++)
      #pragma unroll
      for (int r = 0; r < 4; r++)
        s[i][r] += fmaxf(acc[i][j][r] + bb, 0.f) * ww;
  }
  #pragma unroll
  for (int mk = 1; mk < 16; mk <<= 1)
    #pragma unroll
    for (int i = 0; i < 2; i++)
      #pragma unroll
      for (int r = 0; r < 4; r++)
        s[i][r] += __shfl_xor(s[i][r], mk);
  if (lr == 0){
    #pragma unroll
    for (int i = 0; i < 2; i++)
      #pragma unroll
      for (int r = 0; r < 4; r++)
        atomicAdd(&zt[m0 + w*32 + i*16 + q*4 + r], s[i][r]);
  }
}

// K_fin: per-t finalize (r5-proven body). grid 1024, 4 t per block.
__global__ __launch_bounds__(256) void k_fin(const float* __restrict__ om,
    const float* __restrict__ z1, const float* __restrict__ z2,
    const float* __restrict__ bg2, const float* __restrict__ bp2,
    float* __restrict__ out0, float* __restrict__ out3,
    unsigned short* __restrict__ obf){
  const int tid = threadIdx.x;
  const int w = tid >> 6, lane = tid & 63;
  const int t = blockIdx.x*4 + w;
  float pm = 0.f;
  if (lane < TB){
    float a = z1[lane*TT + t] + bg2[0];
    float b = z2[lane*TT + t] + bp2[0];
    float gate = 1.f/(1.f + expf(-a));
    float sp = (b > 0.f) ? (b + log1pf(expf(-b))) : log1pf(expf(b));
    pm = gate * sp;
  }
  #pragma unroll
  for (int m = 1; m < 4; m <<= 1) pm += __shfl_xor(pm, m);
  pm = __shfl(pm, 0) * 0.25f;
  float4 x = *(const float4*)(om + (size_t)t*DD + lane*4);
  float ss = x.x*x.x + x.y*x.y + x.z*x.z + x.w*x.w;
  #pragma unroll
  for (int m = 1; m < 64; m <<= 1) ss += __shfl_xor(ss, m);
  const float nrm = sqrtf(ss);
  const float sc = pm / fmaxf(nrm, 1e-8f);
  float4 ob = {x.x*sc, x.y*sc, x.z*sc, x.w*sc};
  *(float4*)(out0 + (size_t)t*DD + lane*4) = ob;
  float s2 = ob.x*ob.x + ob.y*ob.y + ob.z*ob.z + ob.w*ob.w;
  #pragma unroll
  for (int m = 1; m < 64; m <<= 1) s2 += __shfl_xor(s2, m);
  const float r2 = sqrtf(s2);
  if (lane == 0) out3[t] = (r2 > 0.05f) ? 1.f : 0.f;
  const float inv2 = 1.f / fmaxf(r2, 1e-8f);
  ushort4 o = {f2bf(ob.x*inv2), f2bf(ob.y*inv2), f2bf(ob.z*inv2), f2bf(ob.w*inv2)};
  *(ushort4*)(obf + (size_t)t*DD + lane*4) = o;
}

// K7: fused sims + masked max/argmax. NEW: 64-row tiles (2x32KB LDS) — halves
// barrier/drain count (16 iterations vs 32) at unchanged 2 blocks/CU.
// Staging = r2-verified 8-instr pattern; compute = r7-verified afr[4] form.
// XCD-grouped (xcd = ns&7).
__global__ __launch_bounds__(256) void k_sims(const unsigned short* __restrict__ obf,
    const unsigned short* __restrict__ bbf, const unsigned char* __restrict__ mask,
    float* __restrict__ pmax, int* __restrict__ pidx){
  const int bid = blockIdx.x;                // 0..511
  const int u = bid >> 3;                    // 0..63
  const int ns = (bid & 7) + ((u >> 4) << 3);   // 0..31; xcd = ns&7
  const int t0 = (u & 15) * 256;
  const int nbase0 = ns * (NN/32);           // 1024-row slice
  const int tid = threadIdx.x;
  const int w = tid >> 6, lane = tid & 63;
  const int lr = lane & 15, q = lane >> 4;
  __shared__ __align__(16) unsigned short bt[2][64*256];   // 2 x 32 KB
  __shared__ __align__(16) unsigned char am[1024];
  const int srow = lane >> 5;
  const int sp   = lane & 31;

  ((unsigned int*)am)[tid] = ((const unsigned int*)(mask + nbase0))[tid];

  #pragma unroll
  for (int i = 0; i < 8; i++){
    const int row = (i*4 + w)*2 + srow;
    const unsigned short* src = bbf + (size_t)(nbase0 + row)*DD + ((sp ^ (row & 31)) << 3);
    gload_ldsv(src, &bt[0][(i*4 + w)*512]);
  }
  bf16x8 afr[4][8];
  #pragma unroll
  for (int i = 0; i < 4; i++){
    const unsigned short* ap = obf + (size_t)(t0 + w*64 + i*16 + lr)*DD + q*8;
    #pragma unroll
    for (int ks = 0; ks < 8; ks++)
      afr[i][ks] = as_bf16x8(*(const uint4*)(ap + ks*32));
  }
  __syncthreads();

  float vmax[4][4]; int vidx[4][4];
  #pragma unroll
  for (int i = 0; i < 4; i++)
    #pragma unroll
    for (int r = 0; r < 4; r++){ vmax[i][r] = -INFINITY; vidx[i][r] = -1; }

  int cur = 0;
  for (int it = 0; it < 16; it++){
    const int nl = it*64;
    if (it < 15){
      #pragma unroll
      for (int i = 0; i < 8; i++){
        const int row = (i*4 + w)*2 + srow;
        const unsigned short* src = bbf + (size_t)(nbase0 + nl + 64 + row)*DD + ((sp ^ (row & 31)) << 3);
        gload_ldsv(src, &bt[cur^1][(i*4 + w)*512]);
      }
    }
    const unsigned short* btc = bt[cur];
    #pragma unroll
    for (int sub = 0; sub < 4; sub++){
      const int rowi = sub*16 + lr;          // 0..63
      const bool act = (am[nl + rowi] != 0);
      const unsigned short* bp = btc + rowi*256;
      const int rx = rowi & 31;
      f32x4 acc[4] = {};
      __builtin_amdgcn_s_setprio(1);
      #pragma unroll
      for (int ks = 0; ks < 8; ks++){
        const int p = (q + ks*4) ^ rx;
        bf16x8 bfr = as_bf16x8(*(const uint4*)(bp + (p & 31)*8));
        #pragma unroll
        for (int i = 0; i < 4; i++)
          acc[i] = __builtin_amdgcn_mfma_f32_16x16x32_bf16(afr[i][ks], bfr, acc[i], 0, 0, 0);
      }
      __builtin_amdgcn_s_setprio(0);
      if (act){
        const int n = nbase0 + nl + rowi;
        #pragma unroll
        for (int i = 0; i < 4; i++)
          #pragma unroll
          for (int r = 0; r < 4; r++)
            if (acc[i][r] > vmax[i][r]){ vmax[i][r] = acc[i][r]; vidx[i][r] = n; }
      }
    }
    __syncthreads();
    cur ^= 1;
  }
  #pragma unroll
  for (int mk = 1; mk < 16; mk <<= 1){
    #pragma unroll
    for (int i = 0; i < 4; i++)
      #pragma unroll
      for (int r = 0; r < 4; r++){
        float om = __shfl_xor(vmax[i][r], mk);
        int   oi = __shfl_xor(vidx[i][r], mk);
        if (om > vmax[i][r] || (om == vmax[i][r] && (unsigned)oi < (unsigned)vidx[i][r])){
          vmax[i][r] = om; vidx[i][r] = oi;
        }
      }
  }
  if (lr == 0){
    #pragma unroll
    for (int i = 0; i < 4; i++)
      #pragma unroll
      for (int r = 0; r < 4; r++){
        const int t = t0 + w*64 + i*16 + q*4 + r;
        pmax[ns*TT + t] = vmax[i][r];
        pidx[ns*TT + t] = vidx[i][r];
      }
  }
}

// K8: combine n-splits + match logic. any_active is implied: if no belief is
// active, every slice keeps best=-INF / bi=-1 -> matched=false -> (0, -1),
// exactly the reference's any_active=false branch.
__global__ __launch_bounds__(256) void k_combine(const float* __restrict__ pmax,
    const int* __restrict__ pidx, const float* __restrict__ out3,
    float* __restrict__ out1, float* __restrict__ out2){
  const int t = blockIdx.x*256 + threadIdx.x;
  float best = -INFINITY; int bi = -1;
  #pragma unroll
  for (int s = 0; s < 32; s++){
    float m = pmax[s*TT + t];
    if (m > best){ best = m; bi = pidx[s*TT + t]; }
  }
  const bool mf = out3[t] != 0.f;
  const bool matched = mf && (best > 0.5f);
  out1[t] = matched ? best : 0.f;
  out2[t] = matched ? (float)bi : -1.f;
}

extern "C" void kernel_launch(void* const* d_in, const int* in_sizes, int n_in,
                              void* d_out, int out_size, void* d_ws, size_t ws_size,
                              hipStream_t stream) {
  const float* hidden = (const float*)d_in[0];
  const float* beliefs = (const float*)d_in[1];
  const unsigned char* amask = (const unsigned char*)d_in[2];
  const float* W_obs = (const float*)d_in[3];
  const float* W_g1 = (const float*)d_in[4];
  const float* b_g1 = (const float*)d_in[5];
  const float* W_g2 = (const float*)d_in[6];
  const float* b_g2 = (const float*)d_in[7];
  const float* W_p1 = (const float*)d_in[8];
  const float* b_p1 = (const float*)d_in[9];
  const float* W_p2 = (const float*)d_in[10];
  const float* b_p2 = (const float*)d_in[11];

  char* ws = (char*)d_ws;
  const size_t HMB_OFF  = 0;                 // 16777216
  const size_t WSW_OFF  = 16777216;          // 4194304 (swizzled)
  const size_t WOB_OFF  = 20971520;          // 1048576
  const size_t OM_OFF   = 22020096;          // 4194304 (f32 obs_mean partials)
  const size_t Z1_OFF   = 26214400;          // 65536
  const size_t Z2_OFF   = 26279936;          // 65536
  const size_t OBF_OFF  = 26362112;          // 2097152
  const size_t BBF_OFF  = 28459264;          // 16777216
  const size_t PMAX_OFF = 45236480;          // 524288
  const size_t PIDX_OFF = 45760768;          // 524288    end ~46.3 MB

  unsigned short* hmb = (unsigned short*)(ws + HMB_OFF);
  unsigned short* Wsw = (unsigned short*)(ws + WSW_OFF);
  unsigned short* wob = (unsigned short*)(ws + WOB_OFF);
  float* om  = (float*)(ws + OM_OFF);
  float* z1  = (float*)(ws + Z1_OFF);
  float* z2  = (float*)(ws + Z2_OFF);
  unsigned short* obf = (unsigned short*)(ws + OBF_OFF);
  unsigned short* bbf = (unsigned short*)(ws + BBF_OFF);
  float* pmax = (float*)(ws + PMAX_OFF);
  int*   pidx = (int*)(ws + PIDX_OFF);

  float* out0 = (float*)d_out;            // [T,D] obs_beliefs
  float* out1 = out0 + (size_t)TT*DD;     // [T] sims_out
  float* out2 = out1 + TT;                // [T] slots
  float* out3 = out2 + TT;                // [T] meaningful

  k_prep    <<<PREP_GRID, 256, 0, stream>>>(hidden, hmb, W_g1, W_p1, Wsw,
                W_obs, wob, beliefs, bbf, (unsigned int*)z1, om);
  k_gpo     <<<768, 256, 0, stream>>>(hidden, Wsw, b_g1, b_p1, W_g2, W_p2,
                z1, z2, hmb, wob, om);
  k_fin     <<<1024, 256, 0, stream>>>(om, z1, z2, b_g2, b_p2, out0, out3, obf);
  k_sims    <<<512, 256, 0, stream>>>(obf, bbf, amask, pmax, pidx);
  k_combine <<<TT/256, 256, 0, stream>>>(pmax, pidx, out3, out1, out2);
}